// Round 1
// baseline (222.396 us; speedup 1.0000x reference)
//
#include <hip/hip_runtime.h>

// GraphConvolution: out[b,n,o] = sum_m adj[n,m] * (F[b,m,:] . W[o,:]) + b[o]
// B=8192, N=4, DIN=1024, DOUT=256. G = F_bf16 @ W_bf16^T via MFMA 16x16x32,
// adj 4x4 mix applied per-lane on fp32 accumulators in the epilogue.
//
// R3: B (W image) has ZERO intra-block reuse (waves own disjoint 64-col
// slices), and W bf16 = 512 KB is L2-resident on every XCD. So the per-kb
// global_load_lds staging of sB was pure overhead (guide Common-mistake #7):
// same L2 bytes now go L2 -> VGPR directly. Only sA stays in LDS (double-
// buffered, 2x9 KB) with ONE raw s_barrier per kb waiting lgkmcnt only --
// vmcnt is never drained, so the A fp32 prefetch and the B loads stay in
// flight across barriers (T4-lite). LDS 47->18 KB, occupancy 2->3 blocks/CU.

#define DIN 1024
#define DOUT 256
#define BM 64
#define KI 16                      // DIN / 64
#define LDB 72                     // sA padded row stride in bf16
#define A_HALFS (BM * LDB)         // 4608 ushorts per A buffer

typedef __bf16 bf16x8 __attribute__((ext_vector_type(8)));
typedef float f32x4 __attribute__((ext_vector_type(4)));
typedef unsigned short u16x8 __attribute__((ext_vector_type(8)));

__device__ __forceinline__ unsigned short f2bf(float f) {
  union { float f; unsigned int u; } v;
  v.f = f;
  unsigned int u = v.u;
  u += 0x7fffu + ((u >> 16) & 1u);   // round-to-nearest-even
  return (unsigned short)(u >> 16);
}

// Pre-kernel: W [256x1024] fp32 -> bf16, same layout (row-major [col][k]).
// No padding needed anymore: gconv reads it straight from L2.
__global__ __launch_bounds__(256) void wprep_kernel(
    const float* __restrict__ W, unsigned short* __restrict__ ws) {
  const int t = blockIdx.x * 256 + threadIdx.x;  // 32768 threads x 8 elems
  const f32x4* src = (const f32x4*)(W + (size_t)t * 8);
  f32x4 a = src[0], b = src[1];
  u16x8 pk;
#pragma unroll
  for (int m = 0; m < 4; ++m) {
    pk[m] = f2bf(a[m]);
    pk[4 + m] = f2bf(b[m]);
  }
  *(u16x8*)(ws + (size_t)t * 8) = pk;
}

__global__ __launch_bounds__(256, 3) void gconv_kernel(
    const float* __restrict__ adj, const float* __restrict__ feat,
    const unsigned short* __restrict__ wbf, const float* __restrict__ bias,
    float* __restrict__ out) {
  __shared__ __align__(16) unsigned short sA[2][A_HALFS];  // double-buffered

  const int tid = threadIdx.x;
  const int bM = blockIdx.x * BM;

  // A staging: thread owns 32-B chunks of rows row0 and row0+32
  const int row0 = tid >> 3;          // 0..31
  const int kc0 = (tid & 7) * 8;
  const float* aptr0 = feat + (size_t)(bM + row0) * DIN + kc0;
  const float* aptr1 = aptr0 + (size_t)32 * DIN;
  unsigned short* sw0 = &sA[0][row0 * LDB + kc0];
  unsigned short* sw1 = &sA[1][row0 * LDB + kc0];

  // wave coords: 1x4 wave grid, 64 rows x 64 cols per wave
  const int lane = tid & 63;
  const int wid = tid >> 6;
  const int wc = wid * 64;
  const int rl = lane & 15;
  const int q = lane >> 4;
  const int q8 = q * 8;

  // per-lane B base: col = wc + j*16 + rl, k = kb*64 + ks*32 + q*8
  const unsigned short* bp0 = wbf + (size_t)(wc + rl) * DIN + q8;

  f32x4 acc[4][4];
#pragma unroll
  for (int i = 0; i < 4; ++i)
#pragma unroll
    for (int j = 0; j < 4; ++j) acc[i][j] = f32x4{0.f, 0.f, 0.f, 0.f};

  // prologue: kb=0 A tile -> regs -> bf16 -> sA[0]
  f32x4 pa0 = *(const f32x4*)aptr0;
  f32x4 pa1 = *(const f32x4*)(aptr0 + 4);
  f32x4 pa2 = *(const f32x4*)aptr1;
  f32x4 pa3 = *(const f32x4*)(aptr1 + 4);
  {
    u16x8 pk0, pk1;
#pragma unroll
    for (int m = 0; m < 4; ++m) {
      pk0[m] = f2bf(pa0[m]);
      pk0[4 + m] = f2bf(pa1[m]);
      pk1[m] = f2bf(pa2[m]);
      pk1[4 + m] = f2bf(pa3[m]);
    }
    *(u16x8*)sw0 = pk0;
    *(u16x8*)(sw0 + 32 * LDB) = pk1;
  }
  // prefetch A for kb=1 (stays in flight across the raw barrier)
  pa0 = *(const f32x4*)(aptr0 + 64);
  pa1 = *(const f32x4*)(aptr0 + 68);
  pa2 = *(const f32x4*)(aptr1 + 64);
  pa3 = *(const f32x4*)(aptr1 + 68);

  for (int kb = 0; kb < KI; ++kb) {
    // B fragments for this kb: direct L2 -> VGPR, issued BEFORE the barrier
    // so their latency hides under the barrier wait (vmcnt not drained).
    bf16x8 bfr[2][4];
#pragma unroll
    for (int ks = 0; ks < 2; ++ks)
#pragma unroll
      for (int j = 0; j < 4; ++j)
        bfr[ks][j] =
            *(const bf16x8*)(bp0 + (size_t)j * 16 * DIN + kb * 64 + ks * 32);

    // raw barrier: wait only LDS ops (sA writes/reads), never vmcnt.
    __builtin_amdgcn_sched_barrier(0);
    asm volatile("s_waitcnt lgkmcnt(0)" ::: "memory");
    __builtin_amdgcn_s_barrier();
    __builtin_amdgcn_sched_barrier(0);

    const unsigned short* sa = (kb & 1) ? &sA[1][0] : &sA[0][0];
#pragma unroll
    for (int ks = 0; ks < 2; ++ks) {
      const int ko = ks * 32 + q8;
      bf16x8 af[4];
#pragma unroll
      for (int i = 0; i < 4; ++i)
        af[i] = *(const bf16x8*)(sa + (i * 16 + rl) * LDB + ko);
#pragma unroll
      for (int i = 0; i < 4; ++i)
#pragma unroll
        for (int j = 0; j < 4; ++j)
          acc[i][j] = __builtin_amdgcn_mfma_f32_16x16x32_bf16(
              af[i], bfr[ks][j], acc[i][j], 0, 0, 0);
    }

    // stage next A tile into the other buffer (no barrier needed here:
    // readers of that buffer finished their ds_reads before the barrier
    // they already passed; visibility handled at next iteration's barrier).
    if (kb + 1 < KI) {
      u16x8 pk0, pk1;
#pragma unroll
      for (int m = 0; m < 4; ++m) {
        pk0[m] = f2bf(pa0[m]);
        pk0[4 + m] = f2bf(pa1[m]);
        pk1[m] = f2bf(pa2[m]);
        pk1[4 + m] = f2bf(pa3[m]);
      }
      unsigned short* sw = ((kb + 1) & 1) ? sw1 : sw0;
      *(u16x8*)sw = pk0;
      *(u16x8*)(sw + 32 * LDB) = pk1;
      if (kb + 2 < KI) {
        const float* a0 = aptr0 + (size_t)(kb + 2) * 64;
        const float* a1 = aptr1 + (size_t)(kb + 2) * 64;
        pa0 = *(const f32x4*)a0;
        pa1 = *(const f32x4*)(a0 + 4);
        pa2 = *(const f32x4*)a1;
        pa3 = *(const f32x4*)(a1 + 4);
      }
    }
  }

  // epilogue: adj 4x4 mix (regs = rows 4q..4q+3 of one batch) + bias
  float am[16];
#pragma unroll
  for (int i = 0; i < 16; ++i) am[i] = adj[i];  // uniform -> scalar loads

  float bv[4];
#pragma unroll
  for (int j = 0; j < 4; ++j) bv[j] = bias[wc + j * 16 + rl];

#pragma unroll
  for (int i = 0; i < 4; ++i) {
    const size_t rowbase = (size_t)(bM + i * 16 + q * 4);
#pragma unroll
    for (int j = 0; j < 4; ++j) {
      const int col = wc + j * 16 + rl;
      float* op = out + rowbase * DOUT + col;
      f32x4 g = acc[i][j];
#pragma unroll
      for (int n = 0; n < 4; ++n) {
        op[(size_t)n * DOUT] = am[n * 4 + 0] * g[0] + am[n * 4 + 1] * g[1] +
                               am[n * 4 + 2] * g[2] + am[n * 4 + 3] * g[3] +
                               bv[j];
      }
    }
  }
}

extern "C" void kernel_launch(void* const* d_in, const int* in_sizes, int n_in,
                              void* d_out, int out_size, void* d_ws,
                              size_t ws_size, hipStream_t stream) {
  const float* adj = (const float*)d_in[0];
  const float* feat = (const float*)d_in[1];
  const float* W = (const float*)d_in[2];
  const float* bias = (const float*)d_in[3];
  float* out = (float*)d_out;
  unsigned short* ws = (unsigned short*)d_ws;  // 256*1024*2 B = 512 KB

  wprep_kernel<<<128, 256, 0, stream>>>(W, ws);
  gconv_kernel<<<8192 * 4 / BM, 256, 0, stream>>>(adj, feat, ws, bias, out);
}